// Round 1
// baseline (4672.012 us; speedup 1.0000x reference)
//
#include <hip/hip_runtime.h>
#include <hip/hip_bf16.h>
#include <stdint.h>

typedef __attribute__((ext_vector_type(8))) short bf16x8;
typedef __attribute__((ext_vector_type(4))) float f32x4;

#define AS1(p) ((const __attribute__((address_space(1))) void*)(p))
#define AS3(p) ((__attribute__((address_space(3))) void*)(p))

__device__ __forceinline__ unsigned short f2bf(float f) {
    union { float f; unsigned u; } v; v.f = f;
    unsigned r = v.u + 0x7fffu + ((v.u >> 16) & 1u);
    return (unsigned short)(r >> 16);
}
__device__ __forceinline__ float bf2f(unsigned short h) {
    union { unsigned u; float f; } v; v.u = ((unsigned)h) << 16;
    return v.f;
}

// ---------------------------------------------------------------------------
// Gather-GEMM: out[N,256] = sum_k in[neigh[:,k]] @ Wt[k]^T   (Wt: [NK,256,CIN] bf16)
// BM=128 rows, BN=128 cols (gridDim.y=2 col tiles), 4 waves (2x2), 16x16x32 MFMA.
// Also accumulates per-column sum / sumsq into stats[2*256] via atomics.
// ---------------------------------------------------------------------------
template<int CIN, bool GATHER, bool OUT_BF16>
__global__ __launch_bounds__(256, 3) void conv_kernel(
    const unsigned short* __restrict__ in,     // [N, CIN] bf16
    const int* __restrict__ neigh,             // [N, 27] (or unused)
    const unsigned short* __restrict__ Wt,     // [NK, 256, CIN] bf16 (transposed weights)
    void* __restrict__ outp,                   // bf16 or f32 [N,256]
    float* __restrict__ stats,                 // [2][256]
    const unsigned short* __restrict__ zerobuf,
    int N, int NK)
{
    constexpr int BM = 128, BN = 128, KT = 64;
    constexpr int NKT = CIN / KT;
    __shared__ unsigned short Alds[BM * KT];   // 16 KB, XOR-swizzled
    __shared__ unsigned short Blds[BN * KT];   // 16 KB, XOR-swizzled
    __shared__ int idx_lds[BM];

    const int tid  = threadIdx.x;
    const int lane = tid & 63;
    const int wid  = tid >> 6;
    const int wr   = wid >> 1, wc = wid & 1;   // wave 2x2 grid, each 64x64
    const int brow = blockIdx.x * BM;
    const int bcol = blockIdx.y * BN;

    f32x4 acc[4][4] = {};

    for (int k = 0; k < NK; ++k) {
        __syncthreads();                        // WAR vs previous compute + idx reuse
        if (tid < BM) {
            int r = brow + tid;
            int g = -1;
            if (r < N) g = GATHER ? neigh[(size_t)r * 27 + k] : r;
            idx_lds[tid] = g;
        }
        __syncthreads();
        for (int kt = 0; kt < NKT; ++kt) {
            if (kt > 0) __syncthreads();        // WAR for LDS tiles
            // --- stage A: 128 gathered rows x 64 bf16 (128B each), swizzled source
            #pragma unroll
            for (int i = 0; i < 4; ++i) {
                int s = i * 256 + tid;
                int r = s >> 3, seg = s & 7;
                int g = idx_lds[r];
                const char* src = (g >= 0)
                    ? (const char*)in + (((size_t)g * CIN + kt * KT) * 2) + ((seg ^ (r & 7)) * 16)
                    : (const char*)zerobuf + seg * 16;
                __builtin_amdgcn_global_load_lds(AS1(src),
                    AS3((char*)Alds + (i * 256 + wid * 64) * 16), 16, 0, 0);
            }
            // --- stage B: 128 weight cols x 64 bf16, coalesced from Wt, swizzled source
            #pragma unroll
            for (int i = 0; i < 4; ++i) {
                int s = i * 256 + tid;
                int c = s >> 3, seg = s & 7;
                const char* src = (const char*)Wt
                    + (((size_t)(k * 256 + bcol + c) * CIN + kt * KT) * 2)
                    + ((seg ^ (c & 7)) * 16);
                __builtin_amdgcn_global_load_lds(AS1(src),
                    AS3((char*)Blds + (i * 256 + wid * 64) * 16), 16, 0, 0);
            }
            __syncthreads();                    // RAW: tiles ready (drains vmcnt)
            // --- fragments + MFMA
            bf16x8 bfr[4][2];
            #pragma unroll
            for (int n = 0; n < 4; ++n)
                #pragma unroll
                for (int kk = 0; kk < 2; ++kk) {
                    int c = wc * 64 + n * 16 + (lane & 15);
                    int byte = (c * 128 + kk * 64 + ((lane >> 4) * 16)) ^ ((c & 7) << 4);
                    bfr[n][kk] = *(const bf16x8*)((const char*)Blds + byte);
                }
            #pragma unroll
            for (int m = 0; m < 4; ++m) {
                bf16x8 af[2];
                #pragma unroll
                for (int kk = 0; kk < 2; ++kk) {
                    int r = wr * 64 + m * 16 + (lane & 15);
                    int byte = (r * 128 + kk * 64 + ((lane >> 4) * 16)) ^ ((r & 7) << 4);
                    af[kk] = *(const bf16x8*)((const char*)Alds + byte);
                }
                #pragma unroll
                for (int n = 0; n < 4; ++n) {
                    acc[m][n] = __builtin_amdgcn_mfma_f32_16x16x32_bf16(af[0], bfr[n][0], acc[m][n], 0, 0, 0);
                    acc[m][n] = __builtin_amdgcn_mfma_f32_16x16x32_bf16(af[1], bfr[n][1], acc[m][n], 0, 0, 0);
                }
            }
        }
    }

    // --- per-column stats (sum, sumsq); padded rows contributed exact zeros
    #pragma unroll
    for (int n = 0; n < 4; ++n) {
        float s = 0.f, q = 0.f;
        #pragma unroll
        for (int m = 0; m < 4; ++m)
            #pragma unroll
            for (int j = 0; j < 4; ++j) { float v = acc[m][n][j]; s += v; q += v * v; }
        s += __shfl_xor(s, 16); s += __shfl_xor(s, 32);
        q += __shfl_xor(q, 16); q += __shfl_xor(q, 32);
        if (lane < 16) {
            int col = bcol + wc * 64 + n * 16 + lane;
            atomicAdd(&stats[col], s);
            atomicAdd(&stats[256 + col], q);
        }
    }
    // --- store raw output (C/D map: col=lane&15, row=(lane>>4)*4+j)
    #pragma unroll
    for (int m = 0; m < 4; ++m) {
        #pragma unroll
        for (int j = 0; j < 4; ++j) {
            int row = brow + wr * 64 + m * 16 + ((lane >> 4) * 4) + j;
            if (row < N) {
                #pragma unroll
                for (int n = 0; n < 4; ++n) {
                    int col = bcol + wc * 64 + n * 16 + (lane & 15);
                    float v = acc[m][n][j];
                    if (OUT_BF16)
                        ((unsigned short*)outp)[(size_t)row * 256 + col] = f2bf(v);
                    else
                        ((float*)outp)[(size_t)row * 256 + col] = v;
                }
            }
        }
    }
}

// ---------------------------------------------------------------------------
// small helper kernels
// ---------------------------------------------------------------------------
__global__ void cast_x_kernel(const float* __restrict__ x, unsigned short* __restrict__ xb, size_t n8) {
    size_t stride = (size_t)gridDim.x * blockDim.x;
    for (size_t i = (size_t)blockIdx.x * blockDim.x + threadIdx.x; i < n8; i += stride) {
        const float4* p = (const float4*)(x + i * 8);
        float4 f0 = p[0], f1 = p[1];
        unsigned short o[8];
        o[0] = f2bf(f0.x); o[1] = f2bf(f0.y); o[2] = f2bf(f0.z); o[3] = f2bf(f0.w);
        o[4] = f2bf(f1.x); o[5] = f2bf(f1.y); o[6] = f2bf(f1.z); o[7] = f2bf(f1.w);
        *(uint4*)(xb + i * 8) = *(uint4*)o;
    }
}

// w: [NK,CI,CO] f32  ->  wt: [NK,CO,CI] bf16
__global__ void cast_wT_kernel(const float* __restrict__ w, unsigned short* __restrict__ wt,
                               int NK, int CI, int CO) {
    int total = NK * CI * CO;
    int stride = gridDim.x * blockDim.x;
    for (int id = blockIdx.x * blockDim.x + threadIdx.x; id < total; id += stride) {
        int ci = id % CI;
        int t  = id / CI;
        int co = t % CO;
        int k  = t / CO;
        wt[id] = f2bf(w[((size_t)k * CI + ci) * CO + co]);
    }
}

__global__ void finalize_kernel(const float* __restrict__ stats, const float* __restrict__ gamma,
                                const float* __restrict__ beta, float* __restrict__ coef, float invN) {
    int c = threadIdx.x;
    float mean = stats[c] * invN;
    float var  = fmaxf(stats[256 + c] * invN - mean * mean, 0.f);
    float a = gamma[c] * rsqrtf(var + 1e-5f);
    coef[c] = a;
    coef[256 + c] = beta[c] - mean * a;
}

// in-place bf16: x = relu(x*a[c] + b[c])
__global__ void bn_relu_kernel(unsigned short* __restrict__ buf, const float* __restrict__ coef, size_t n8) {
    size_t stride = (size_t)gridDim.x * blockDim.x;
    for (size_t i = (size_t)blockIdx.x * blockDim.x + threadIdx.x; i < n8; i += stride) {
        uint4 v = *(uint4*)(buf + i * 8);
        unsigned short* h = (unsigned short*)&v;
        int cb = (int)((i * 8) & 255);
        #pragma unroll
        for (int j = 0; j < 8; ++j) {
            float f = bf2f(h[j]) * coef[cb + j] + coef[256 + cb + j];
            h[j] = f2bf(fmaxf(f, 0.f));
        }
        *(uint4*)(buf + i * 8) = v;
    }
}

// out = relu(out*a2+b2 + sc*as+bs), out f32 in-place, sc bf16
__global__ void final_kernel(float* __restrict__ out, const unsigned short* __restrict__ sc,
                             const float* __restrict__ c2, const float* __restrict__ cs, size_t n4) {
    size_t stride = (size_t)gridDim.x * blockDim.x;
    for (size_t i = (size_t)blockIdx.x * blockDim.x + threadIdx.x; i < n4; i += stride) {
        float4 o = *(float4*)(out + i * 4);
        ushort4 s4 = *(const ushort4*)(sc + i * 4);
        int cb = (int)((i * 4) & 255);
        float r;
        r = o.x * c2[cb + 0] + c2[256 + cb + 0] + bf2f(s4.x) * cs[cb + 0] + cs[256 + cb + 0]; o.x = fmaxf(r, 0.f);
        r = o.y * c2[cb + 1] + c2[256 + cb + 1] + bf2f(s4.y) * cs[cb + 1] + cs[256 + cb + 1]; o.y = fmaxf(r, 0.f);
        r = o.z * c2[cb + 2] + c2[256 + cb + 2] + bf2f(s4.z) * cs[cb + 2] + cs[256 + cb + 2]; o.z = fmaxf(r, 0.f);
        r = o.w * c2[cb + 3] + c2[256 + cb + 3] + bf2f(s4.w) * cs[cb + 3] + cs[256 + cb + 3]; o.w = fmaxf(r, 0.f);
        *(float4*)(out + i * 4) = o;
    }
}

// ---------------------------------------------------------------------------
extern "C" void kernel_launch(void* const* d_in, const int* in_sizes, int n_in,
                              void* d_out, int out_size, void* d_ws, size_t ws_size,
                              hipStream_t stream) {
    const float* data = (const float*)d_in[0];
    const int*   neigh = (const int*)d_in[1];
    // d_in[2] = depth (unused)
    const float* Wa = (const float*)d_in[3];
    const float* ga = (const float*)d_in[4];
    const float* ba = (const float*)d_in[5];
    const float* Wb = (const float*)d_in[6];
    const float* gb = (const float*)d_in[7];
    const float* bb = (const float*)d_in[8];
    const float* W1 = (const float*)d_in[9];
    const float* gs = (const float*)d_in[10];
    const float* bs = (const float*)d_in[11];

    const int N = in_sizes[0] / 128;

    // ws layout
    char* ws = (char*)d_ws;
    float* stats1 = (float*)(ws + 0);        // [2][256]
    float* stats2 = (float*)(ws + 2048);
    float* statss = (float*)(ws + 4096);
    float* c1     = (float*)(ws + 6144);     // [2][256] scale/shift
    float* c2     = (float*)(ws + 8192);
    float* cs     = (float*)(ws + 10240);
    unsigned short* zerobuf = (unsigned short*)(ws + 12288);  // 256B zeros
    unsigned short* WaT = (unsigned short*)(ws + 16384);      // [27][256][128]
    unsigned short* WbT = WaT + (size_t)27 * 256 * 128;       // [27][256][256]
    unsigned short* W1T = WbT + (size_t)27 * 256 * 256;       // [256][128]
    unsigned short* Xb  = W1T + (size_t)256 * 128;            // [N][128] bf16
    unsigned short* buf1 = Xb + (size_t)N * 128;              // [N][256] bf16 (conv1 raw/norm, later shortcut)

    hipMemsetAsync(d_ws, 0, 16384, stream);   // stats + coefs + zerobuf

    cast_x_kernel<<<2048, 256, 0, stream>>>(data, Xb, (size_t)N * 128 / 8);
    cast_wT_kernel<<<1024, 256, 0, stream>>>(Wa, WaT, 27, 128, 256);
    cast_wT_kernel<<<1024, 256, 0, stream>>>(Wb, WbT, 27, 256, 256);
    cast_wT_kernel<<<64, 256, 0, stream>>>(W1, W1T, 1, 128, 256);

    dim3 cgrid((N + 127) / 128, 2);
    // conv1: gather Xb -> raw bf16 + stats1
    conv_kernel<128, true, true><<<cgrid, 256, 0, stream>>>(Xb, neigh, WaT, buf1, stats1, zerobuf, N, 27);
    finalize_kernel<<<1, 256, 0, stream>>>(stats1, ga, ba, c1, 1.0f / N);
    bn_relu_kernel<<<2048, 256, 0, stream>>>(buf1, c1, (size_t)N * 256 / 8);
    // conv2: gather normalized conv1 -> raw f32 into d_out + stats2
    conv_kernel<256, true, false><<<cgrid, 256, 0, stream>>>(buf1, neigh, WbT, d_out, stats2, zerobuf, N, 27);
    // shortcut: dense Xb @ W1 -> raw bf16 (reuse buf1) + statss
    conv_kernel<128, false, true><<<cgrid, 256, 0, stream>>>(Xb, nullptr, W1T, buf1, statss, zerobuf, N, 1);
    finalize_kernel<<<1, 256, 0, stream>>>(stats2, gb, bb, c2, 1.0f / N);
    finalize_kernel<<<1, 256, 0, stream>>>(statss, gs, bs, cs, 1.0f / N);
    // out = relu(bn(conv2) + bn(shortcut))
    final_kernel<<<2048, 256, 0, stream>>>((float*)d_out, buf1, c2, cs, (size_t)N * 256 / 4);
}